// Round 1
// baseline (85.255 us; speedup 1.0000x reference)
//
#include <hip/hip_runtime.h>

// CooccurrenceMatrix: C[b,r,s] = sum_{i,j} [a[b,r,i]==a[b,s,j] & mr_i>0 & ms_j>0] * K[i,j]
//                              / (valid_r * valid_s + 1e-8)
//
// Algorithm: per (b,r), build h[v][j] = sum_i [a_r_i==v & mr_i>0] * K[i,j] in LDS
// (20x20 floats). Then C[b,r,s] = sum_j [ms_j>0] * h[a_s_j][j]  -- 20 LDS gathers
// per output element instead of 400 FMAs (20x work reduction).
// One block per (b,r): 128 threads = W, thread s computes C[b,r,s].

#define BB 16
#define WW 128
#define LL 20

__global__ __launch_bounds__(128) void coocc_kernel(
    const int*   __restrict__ a,     // [B,W,L] int32
    const float* __restrict__ mask,  // [B,W,L] f32
    const float* __restrict__ kern,  // [L,L]   f32
    float*       __restrict__ out)   // [B,W,W] f32
{
    __shared__ float K_lds[LL * LL];
    __shared__ float h[LL * LL];
    __shared__ int   a_r[LL];
    __shared__ float m_r[LL];

    const int t   = threadIdx.x;
    const int bid = blockIdx.x;     // = b*W + r
    const int b   = bid / WW;

    // ---- stage K, a_r, m_r into LDS ----
    for (int e = t; e < LL * LL; e += 128) K_lds[e] = kern[e];
    if (t < LL) {
        a_r[t] = a[bid * LL + t];
        m_r[t] = mask[bid * LL + t];
    }
    __syncthreads();

    // ---- phase 1: h[v*L+j] = sum_i [a_r[i]==v & m_r[i]>0] * K[i*L+j] ----
    for (int e = t; e < LL * LL; e += 128) {
        const int v = e / LL;
        const int j = e - v * LL;
        float acc = 0.f;
        #pragma unroll
        for (int i = 0; i < LL; ++i) {
            const bool m = (a_r[i] == v) && (m_r[i] > 0.f);
            acc += m ? K_lds[i * LL + j] : 0.f;
        }
        h[e] = acc;
    }
    __syncthreads();

    // valid_r: broadcast LDS reads, cheap
    float valid_r = 0.f;
    #pragma unroll
    for (int i = 0; i < LL; ++i) valid_r += m_r[i];

    // ---- phase 2: thread t = s in [0,128) ----
    const int s    = t;
    const int base = (b * WW + s) * LL;
    float acc = 0.f, valid_s = 0.f;
    #pragma unroll
    for (int j = 0; j < LL; ++j) {
        const int   v  = a[base + j];
        const float ms = mask[base + j];
        valid_s += ms;
        acc += (ms > 0.f) ? h[v * LL + j] : 0.f;
    }
    out[bid * WW + s] = acc / (valid_r * valid_s + 1e-8f);
}

extern "C" void kernel_launch(void* const* d_in, const int* in_sizes, int n_in,
                              void* d_out, int out_size, void* d_ws, size_t ws_size,
                              hipStream_t stream) {
    const int*   a    = (const int*)  d_in[0];  // anonymized_nodes [B,W,L]
    const float* mask = (const float*)d_in[1];  // walk_masks       [B,W,L]
    const float* kern = (const float*)d_in[2];  // kernel           [L,L]
    float*       out  = (float*)d_out;          // [B,W,W]

    coocc_kernel<<<BB * WW, 128, 0, stream>>>(a, mask, kern, out);
}

// Round 2
// 63.863 us; speedup vs baseline: 1.3350x; 1.3350x over previous
//
#include <hip/hip_runtime.h>

// CooccurrenceMatrix: C[b,r,s] = sum_{i,j} [a[b,r,i]==a[b,s,j] & mr_i>0 & ms_j>0] * K[i,j]
//                              / (valid_r * valid_s + 1e-8)
//
// R1: scatter h-build. Per (b,r): h[v][j] = sum_i [a_r_i==v & mr_i>0] * K[i,j]
// built via LDS float atomics: for each (i,j), h[a_r[i]*20+j] += K[i][j]
// (400 lane-ops, ~7 wave-instrs) instead of the gather form's 8000 K-reads
// (~400 LDS wave-instrs). K read coalesced straight from global (1.6 KB, L1-hot).
// Phase-2 row loads hoisted to kernel start (int4/float4 x5, 80B rows are 16B
// aligned) so global latency overlaps phase 1. valid_r via one wave-0 shuffle
// reduce instead of 20 broadcast reads per thread.
// One block per (b,r): 128 threads = W, thread t computes C[b,r,t].

#define BB 16
#define WW 128
#define LL 20

__global__ __launch_bounds__(128) void coocc_kernel(
    const int*   __restrict__ a,     // [B,W,L] int32
    const float* __restrict__ mask,  // [B,W,L] f32
    const float* __restrict__ kern,  // [L,L]   f32
    float*       __restrict__ out)   // [B,W,W] f32
{
    __shared__ float h[LL * LL];
    __shared__ int   am_r[LL];       // a_r[i] if m_r[i]>0 else -1
    __shared__ float vr_sh;

    const int t   = threadIdx.x;
    const int bid = blockIdx.x;      // = b*W + r
    const int b   = bid >> 7;        // /128

    // ---- hoisted phase-2 loads: this thread's s-row (s = t) ----
    // byte offset = base*4 = 80*(b*128+t) -> 16B aligned, int4/float4 legal
    const int base = (b * WW + t) * LL;
    int4   av[5];
    float4 mv[5];
    const int4*   ap = (const int4*)  (a    + base);
    const float4* mp = (const float4*)(mask + base);
    #pragma unroll
    for (int q = 0; q < 5; ++q) { av[q] = ap[q]; mv[q] = mp[q]; }

    // ---- stage r-row as masked values; wave-0 reduce for valid_r ----
    float m_own = 0.f;
    if (t < LL) {
        const int   va = a[bid * LL + t];
        const float mm = mask[bid * LL + t];
        am_r[t] = (mm > 0.f) ? va : -1;
        m_own = mm;
    }
    if (t < 64) {                    // wave 0 only; lanes >=20 contribute 0
        float v = m_own;
        #pragma unroll
        for (int off = 32; off; off >>= 1) v += __shfl_xor(v, off, 64);
        if (t == 0) vr_sh = v;
    }

    // ---- zero h (400 floats = 100 float4) ----
    if (t < 100) ((float4*)h)[t] = make_float4(0.f, 0.f, 0.f, 0.f);
    __syncthreads();

    // ---- phase 1: scatter  h[am_r[i]*L + j] += K[i*L + j] ----
    #pragma unroll
    for (int rep = 0; rep < 4; ++rep) {
        const int e = t + rep * 128;
        if (e < LL * LL) {
            const int   i  = e / LL;
            const int   j  = e - i * LL;
            const int   v  = am_r[i];        // near-broadcast LDS read
            const float kv = kern[e];        // coalesced, L1-hot (1.6 KB)
            if (v >= 0) atomicAdd(&h[v * LL + j], kv);   // ds_add_f32
        }
    }
    __syncthreads();

    // ---- phase 2: thread t = s;  C = sum_j [ms_j>0] * h[a_s_j*L + j] ----
    const float valid_r = vr_sh;
    float acc = 0.f, valid_s = 0.f;
    #pragma unroll
    for (int q = 0; q < 5; ++q) {
        const int   aa[4] = {av[q].x, av[q].y, av[q].z, av[q].w};
        const float mm[4] = {mv[q].x, mv[q].y, mv[q].z, mv[q].w};
        #pragma unroll
        for (int k = 0; k < 4; ++k) {
            const int j = q * 4 + k;
            valid_s += mm[k];
            const float hv = h[aa[k] * LL + j];          // LDS gather
            acc += (mm[k] > 0.f) ? hv : 0.f;
        }
    }
    out[bid * WW + t] = acc / (valid_r * valid_s + 1e-8f);
}

extern "C" void kernel_launch(void* const* d_in, const int* in_sizes, int n_in,
                              void* d_out, int out_size, void* d_ws, size_t ws_size,
                              hipStream_t stream) {
    const int*   a    = (const int*)  d_in[0];  // anonymized_nodes [B,W,L]
    const float* mask = (const float*)d_in[1];  // walk_masks       [B,W,L]
    const float* kern = (const float*)d_in[2];  // kernel           [L,L]
    float*       out  = (float*)d_out;          // [B,W,W]

    coocc_kernel<<<BB * WW, 128, 0, stream>>>(a, mask, kern, out);
}